// Round 10
// baseline (1316.159 us; speedup 1.0000x reference)
//
#include <hip/hip_runtime.h>
#include <cstdint>
#include <cstddef>

#define SCALE_ATT 0.125f

typedef unsigned short u16;
typedef __attribute__((ext_vector_type(4))) float f32x4;
typedef __attribute__((ext_vector_type(8))) short bf16x8;
typedef __attribute__((ext_vector_type(4))) u16 u16x4;
typedef __attribute__((ext_vector_type(8))) u16 u16x8;

__device__ __forceinline__ float b2f(u16 u) {
  unsigned int x = ((unsigned int)u) << 16;
  float f;
  __builtin_memcpy(&f, &x, 4);
  return f;
}
__device__ __forceinline__ u16 f2b(float f) {
  unsigned int x;
  __builtin_memcpy(&x, &f, 4);
  unsigned int r = x + 0x7FFFu + ((x >> 16) & 1u);
  return (u16)(r >> 16);
}
__device__ __forceinline__ float gelu_f(float x) {
  return 0.5f * x * (1.0f + erff(x * 0.7071067811865475f));
}

// ---------------- fp32 -> bf16 weight conversion (one launch, 16 tensors) ----------------
struct CvtArgs {
  const float* src[16];
  u16* dst[16];
  int n[16];
};

__global__ __launch_bounds__(256) void cvt_kernel(CvtArgs a) {
  int t = blockIdx.y;
  const float* s = a.src[t];
  u16* d = a.dst[t];
  int n = a.n[t];
  int idx = (blockIdx.x * 256 + threadIdx.x) * 8;
  if (idx >= n) return;
  f32x4 v0 = *(const f32x4*)(s + idx);
  f32x4 v1 = *(const f32x4*)(s + idx + 4);
  u16x8 o;
#pragma unroll
  for (int j = 0; j < 4; ++j) { o[j] = f2b(v0[j]); o[4 + j] = f2b(v1[j]); }
  *(u16x8*)(d + idx) = o;
}

// ---------------- LayerNorm: 1 wave per row of 768; x fp32 or bf16, g/b fp32 ----------------
template <bool XF32>
__global__ __launch_bounds__(256) void ln_kernel(
    const void* xv, const float* __restrict__ g,
    const float* __restrict__ b, u16* __restrict__ out, int M)
{
  int row = blockIdx.x * 4 + (threadIdx.x >> 6);
  int lane = threadIdx.x & 63;
  if (row >= M) return;
  float v[12];
  float s = 0.f;
#pragma unroll
  for (int p = 0; p < 3; ++p) {
    if constexpr (XF32) {
      const float* xr = (const float*)xv + (size_t)row * 768;
      f32x4 t = *(const f32x4*)(xr + p * 256 + lane * 4);
#pragma unroll
      for (int j = 0; j < 4; ++j) { v[p * 4 + j] = t[j]; s += t[j]; }
    } else {
      const u16* xr = (const u16*)xv + (size_t)row * 768;
      u16x4 t = *(const u16x4*)(xr + p * 256 + lane * 4);
#pragma unroll
      for (int j = 0; j < 4; ++j) { v[p * 4 + j] = b2f(t[j]); s += v[p * 4 + j]; }
    }
  }
#pragma unroll
  for (int m = 1; m < 64; m <<= 1) s += __shfl_xor(s, m);
  float mean = s * (1.f / 768.f);
  float q = 0.f;
#pragma unroll
  for (int i = 0; i < 12; ++i) { float d = v[i] - mean; q += d * d; }
#pragma unroll
  for (int m = 1; m < 64; m <<= 1) q += __shfl_xor(q, m);
  float inv = rsqrtf(q * (1.f / 768.f) + 1e-6f);
  u16* orow = out + (size_t)row * 768;
#pragma unroll
  for (int p = 0; p < 3; ++p) {
    f32x4 gg = *(const f32x4*)(g + p * 256 + lane * 4);
    f32x4 bb = *(const f32x4*)(b + p * 256 + lane * 4);
    u16x4 o;
#pragma unroll
    for (int j = 0; j < 4; ++j)
      o[j] = f2b((v[p * 4 + j] - mean) * inv * gg[j] + bb[j]);
    *(u16x4*)(orow + p * 256 + lane * 4) = o;
  }
}

// ---------------- GEMM: C = A(MxK) * W(NxK)^T + bias(fp32), bf16 A/W ----------------
// EPI: 0 = bias only, 1 = bias+GELU(exact), 2 = bias + R1, 3 = bias + R1 + R2
// R1F32: R1 is fp32 (direct input residual); R2 always bf16.
// OUTF32: C is fp32 (the two d_out-writing GEMMs); else bf16.
template <int EPI, bool R1F32, bool OUTF32>
__global__ __launch_bounds__(256, 2) void gemm_nt(
    const u16* __restrict__ A, const u16* __restrict__ W,
    const float* __restrict__ bias, void* __restrict__ Cv,
    const void* __restrict__ R1v, const u16* __restrict__ R2,
    int M, int N, int K)
{
  __shared__ short As[128 * 32];
  __shared__ short Ws[128 * 32];
  const int tid = threadIdx.x;
  const int lane = tid & 63;
  const int wave = tid >> 6;
  const int wm = wave >> 1, wn = wave & 1;
  const int m0 = blockIdx.y * 128, n0 = blockIdx.x * 128;
  const int g16 = lane >> 4, l16 = lane & 15;

  f32x4 acc[4][4];
#pragma unroll
  for (int i = 0; i < 4; ++i)
#pragma unroll
    for (int j = 0; j < 4; ++j) acc[i][j] = f32x4{0.f, 0.f, 0.f, 0.f};

  const int nk = K >> 5;
  for (int kb = 0; kb < nk; ++kb) {
    const int k0 = kb << 5;
    bf16x8 va[2], vw[2];
#pragma unroll
    for (int i = 0; i < 2; ++i) {
      int o = i * 2048 + tid * 8;
      int r = o >> 5, c = o & 31;
      int ra = m0 + r; ra = ra < M ? ra : M - 1;
      int rw = n0 + r; rw = rw < N ? rw : N - 1;
      va[i] = *(const bf16x8*)(A + (size_t)ra * K + k0 + c);
      vw[i] = *(const bf16x8*)(W + (size_t)rw * K + k0 + c);
    }
    __syncthreads();
#pragma unroll
    for (int i = 0; i < 2; ++i) {
      int o = i * 2048 + tid * 8;
      *(bf16x8*)&As[o] = va[i];
      *(bf16x8*)&Ws[o] = vw[i];
    }
    __syncthreads();
    bf16x8 af[4], bfr[4];
#pragma unroll
    for (int mi = 0; mi < 4; ++mi)
      af[mi] = *(const bf16x8*)&As[(wm * 64 + mi * 16 + l16) * 32 + g16 * 8];
#pragma unroll
    for (int ni = 0; ni < 4; ++ni)
      bfr[ni] = *(const bf16x8*)&Ws[(wn * 64 + ni * 16 + l16) * 32 + g16 * 8];
#pragma unroll
    for (int mi = 0; mi < 4; ++mi)
#pragma unroll
      for (int ni = 0; ni < 4; ++ni)
        acc[mi][ni] = __builtin_amdgcn_mfma_f32_16x16x32_bf16(af[mi], bfr[ni], acc[mi][ni], 0, 0, 0);
  }

  const int rbase = m0 + wm * 64 + g16 * 4;
  const int cbase = n0 + wn * 64 + l16;
#pragma unroll
  for (int ni = 0; ni < 4; ++ni) {
    int col = cbase + ni * 16;
    if (col >= N) continue;
    float bv = bias[col];
#pragma unroll
    for (int mi = 0; mi < 4; ++mi) {
#pragma unroll
      for (int j = 0; j < 4; ++j) {
        int row = rbase + mi * 16 + j;
        if (row >= M) continue;
        float v = acc[mi][ni][j] + bv;
        if (EPI == 1) v = gelu_f(v);
        size_t off = (size_t)row * N + col;
        if (EPI == 2 || EPI == 3) {
          if constexpr (R1F32) v += ((const float*)R1v)[off];
          else v += b2f(((const u16*)R1v)[off]);
        }
        if (EPI == 3) v += b2f(R2[off]);
        if constexpr (OUTF32) ((float*)Cv)[off] = v;
        else ((u16*)Cv)[off] = f2b(v);
      }
    }
  }
}

// ---------------- Flash attention, 1 wave per (b,h,32-row q tile), all bf16 internal ----------------
__global__ __launch_bounds__(64) void attn_kernel(
    const u16* __restrict__ q, int qstride,
    const u16* __restrict__ k, const u16* __restrict__ v, int kvstride,
    u16* __restrict__ out, int Sq, int Skv)
{
  __shared__ short P[32 * 32];
  const int lane = threadIdx.x;
  const int g16 = lane >> 4, l16 = lane & 15;
  const int h = blockIdx.y, b = blockIdx.z;
  const int q0 = blockIdx.x * 32;
  const size_t bq = (size_t)b * Sq;
  const size_t bk = (size_t)b * Skv;
  const int hoff = h * 64;

  bf16x8 aq[2][2];
#pragma unroll
  for (int qf = 0; qf < 2; ++qf) {
    int qr = q0 + qf * 16 + l16;
    qr = qr < Sq ? qr : Sq - 1;
#pragma unroll
    for (int dk = 0; dk < 2; ++dk)
      aq[qf][dk] = *(const bf16x8*)(q + (bq + qr) * qstride + hoff + dk * 32 + g16 * 8);
  }

  float mrow[2][4], lrow[2][4];
  f32x4 o[2][4];
#pragma unroll
  for (int qf = 0; qf < 2; ++qf)
#pragma unroll
    for (int j = 0; j < 4; ++j) { mrow[qf][j] = -3.0e38f; lrow[qf][j] = 0.f; }
#pragma unroll
  for (int qf = 0; qf < 2; ++qf)
#pragma unroll
    for (int df = 0; df < 4; ++df) o[qf][df] = f32x4{0.f, 0.f, 0.f, 0.f};

  const int nkb = (Skv + 31) >> 5;
  for (int kb = 0; kb < nkb; ++kb) {
    const int k0 = kb * 32;
    bf16x8 bkf[2][2];
#pragma unroll
    for (int kf = 0; kf < 2; ++kf) {
      int kr = k0 + kf * 16 + l16;
      kr = kr < Skv ? kr : Skv - 1;
#pragma unroll
      for (int dk = 0; dk < 2; ++dk)
        bkf[kf][dk] = *(const bf16x8*)(k + (bk + kr) * kvstride + hoff + dk * 32 + g16 * 8);
    }
    f32x4 s[2][2];
#pragma unroll
    for (int qf = 0; qf < 2; ++qf)
#pragma unroll
      for (int kf = 0; kf < 2; ++kf) {
        f32x4 z = f32x4{0.f, 0.f, 0.f, 0.f};
        z = __builtin_amdgcn_mfma_f32_16x16x32_bf16(aq[qf][0], bkf[kf][0], z, 0, 0, 0);
        z = __builtin_amdgcn_mfma_f32_16x16x32_bf16(aq[qf][1], bkf[kf][1], z, 0, 0, 0);
        s[qf][kf] = z;
      }
    const bool valid0 = (k0 + l16) < Skv;
    const bool valid1 = (k0 + 16 + l16) < Skv;
#pragma unroll
    for (int qf = 0; qf < 2; ++qf) {
      float sf_[4];
#pragma unroll
      for (int j = 0; j < 4; ++j) {
        float v0 = valid0 ? s[qf][0][j] * SCALE_ATT : -3.0e38f;
        float v1 = valid1 ? s[qf][1][j] * SCALE_ATT : -3.0e38f;
        float bm = fmaxf(v0, v1);
#pragma unroll
        for (int m = 1; m < 16; m <<= 1) bm = fmaxf(bm, __shfl_xor(bm, m));
        float mo = mrow[qf][j];
        float mn = fmaxf(mo, bm);
        float sf = __expf(mo - mn);
        mrow[qf][j] = mn;
        float p0 = valid0 ? __expf(v0 - mn) : 0.f;
        float p1 = valid1 ? __expf(v1 - mn) : 0.f;
        float ps = p0 + p1;
#pragma unroll
        for (int m = 1; m < 16; m <<= 1) ps += __shfl_xor(ps, m);
        lrow[qf][j] = lrow[qf][j] * sf + ps;
        sf_[j] = sf;
        s[qf][0][j] = p0;
        s[qf][1][j] = p1;
      }
#pragma unroll
      for (int df = 0; df < 4; ++df)
#pragma unroll
        for (int j = 0; j < 4; ++j)
          o[qf][df][j] *= sf_[j];
    }
    __syncthreads();
#pragma unroll
    for (int qf = 0; qf < 2; ++qf)
#pragma unroll
      for (int kf = 0; kf < 2; ++kf)
#pragma unroll
        for (int j = 0; j < 4; ++j)
          P[(qf * 16 + g16 * 4 + j) * 32 + kf * 16 + l16] = (short)f2b(s[qf][kf][j]);
    __syncthreads();
    bf16x8 pa[2];
#pragma unroll
    for (int qf = 0; qf < 2; ++qf)
      pa[qf] = *(const bf16x8*)&P[(qf * 16 + l16) * 32 + g16 * 8];
    bf16x8 bv[4];
#pragma unroll
    for (int df = 0; df < 4; ++df) {
#pragma unroll
      for (int j = 0; j < 8; ++j) {
        int vr = k0 + g16 * 8 + j;
        vr = vr < Skv ? vr : Skv - 1;
        ((u16*)&bv[df])[j] = v[(bk + vr) * kvstride + hoff + df * 16 + l16];
      }
    }
#pragma unroll
    for (int qf = 0; qf < 2; ++qf)
#pragma unroll
      for (int df = 0; df < 4; ++df)
        o[qf][df] = __builtin_amdgcn_mfma_f32_16x16x32_bf16(pa[qf], bv[df], o[qf][df], 0, 0, 0);
  }
#pragma unroll
  for (int qf = 0; qf < 2; ++qf) {
#pragma unroll
    for (int j = 0; j < 4; ++j) {
      int row = q0 + qf * 16 + g16 * 4 + j;
      if (row >= Sq) continue;
      float invl = 1.f / lrow[qf][j];
      u16* orow = out + (bq + row) * 768 + hoff + l16;
#pragma unroll
      for (int df = 0; df < 4; ++df)
        orow[df * 16] = f2b(o[qf][df][j] * invl);
    }
  }
}

// ---------------- t2s attention: seq len 8, 1 wave per (bn, h), bf16 internal ----------------
__global__ __launch_bounds__(256) void attn_small_kernel(
    const u16* __restrict__ q, const u16* __restrict__ kv, u16* __restrict__ out)
{
  int wid = (blockIdx.x * 256 + threadIdx.x) >> 6;   // 0 .. 9407
  int lane = threadIdx.x & 63;
  int h = wid % 12, bn = wid / 12;                   // bn < 784
  const u16* qb = q + (size_t)bn * 8 * 768 + h * 64;
  const u16* kb = kv + (size_t)bn * 8 * 1536 + h * 64;
  const u16* vb = kb + 768;
  int qi = lane >> 3, ki = lane & 7;
  float s = 0.f;
#pragma unroll
  for (int d = 0; d < 64; d += 4) {
    u16x4 qv = *(const u16x4*)(qb + (size_t)qi * 768 + d);
    u16x4 kvv = *(const u16x4*)(kb + (size_t)ki * 1536 + d);
#pragma unroll
    for (int j = 0; j < 4; ++j) s += b2f(qv[j]) * b2f(kvv[j]);
  }
  s *= SCALE_ATT;
  float m = s;
#pragma unroll
  for (int msk = 1; msk < 8; msk <<= 1) m = fmaxf(m, __shfl_xor(m, msk));
  float p = __expf(s - m);
  float sum = p;
#pragma unroll
  for (int msk = 1; msk < 8; msk <<= 1) sum += __shfl_xor(sum, msk);
  p /= sum;
  float acc[8];
#pragma unroll
  for (int j = 0; j < 8; ++j) acc[j] = 0.f;
#pragma unroll
  for (int kk = 0; kk < 8; ++kk) {
    float pk = __shfl(p, (lane & 56) + kk);
    u16x8 vv = *(const u16x8*)(vb + (size_t)kk * 1536 + ki * 8);
#pragma unroll
    for (int j = 0; j < 8; ++j) acc[j] += pk * b2f(vv[j]);
  }
  u16x8 ov;
#pragma unroll
  for (int j = 0; j < 8; ++j) ov[j] = f2b(acc[j]);
  *(u16x8*)(out + (size_t)(bn * 8 + qi) * 768 + h * 64 + ki * 8) = ov;
}

// ---------------- plumbing kernels (1 row per block, 256 threads); pos is fp32 input ----------------
__global__ __launch_bounds__(256) void add_pos_mod_kernel(
    const u16* __restrict__ in, const float* __restrict__ pos, u16* __restrict__ out, int mod)
{
  int r = blockIdx.x, c = threadIdx.x;
  const u16* ir = in + (size_t)r * 768;
  const float* pr = pos + (size_t)(r % mod) * 768;
  u16* orow = out + (size_t)r * 768;
#pragma unroll
  for (int kk = 0; kk < 3; ++kk) {
    int cc = c + kk * 256;
    orow[cc] = f2b(b2f(ir[cc]) + pr[cc]);
  }
}

__global__ __launch_bounds__(256) void gather_spat_kernel(
    const u16* __restrict__ sn, const float* __restrict__ pos, u16* __restrict__ out)
{
  int r = blockIdx.x, c = threadIdx.x;
  int bt = r / 196, n = r - bt * 196;
  const u16* src = sn + (size_t)(bt * 197 + 1 + n) * 768;
  const float* pr = pos + (size_t)n * 768;
  u16* orow = out + (size_t)r * 768;
#pragma unroll
  for (int kk = 0; kk < 3; ++kk) {
    int cc = c + kk * 256;
    orow[cc] = f2b(b2f(src[cc]) + pr[cc]);
  }
}

// out[(b*196+n)*8 + t] = sn[(b*8+t)*197 + 1 + n] + ctp[t]
__global__ __launch_bounds__(256) void gather_spt2_kernel(
    const u16* __restrict__ sn, const float* __restrict__ ctp, u16* __restrict__ out)
{
  int r = blockIdx.x, c = threadIdx.x;
  int bn = r >> 3, t = r & 7;
  int b = bn / 196, n = bn - b * 196;
  const u16* src = sn + (size_t)((b * 8 + t) * 197 + 1 + n) * 768;
  const float* pr = ctp + (size_t)t * 768;
  u16* orow = out + (size_t)r * 768;
#pragma unroll
  for (int kk = 0; kk < 3; ++kk) {
    int cc = c + kk * 256;
    orow[cc] = f2b(b2f(src[cc]) + pr[cc]);
  }
}

// out[(b*196+n)*8 + t] = tn2[b*1568 + t*196 + n] + vtp[t]
__global__ __launch_bounds__(256) void gather_tt2_kernel(
    const u16* __restrict__ tn2, const float* __restrict__ vtp, u16* __restrict__ out)
{
  int r = blockIdx.x, c = threadIdx.x;
  int bn = r >> 3, t = r & 7;
  int b = bn / 196, n = bn - b * 196;
  const u16* src = tn2 + (size_t)(b * 1568 + t * 196 + n) * 768;
  const float* pr = vtp + (size_t)t * 768;
  u16* orow = out + (size_t)r * 768;
#pragma unroll
  for (int kk = 0; kk < 3; ++kk) {
    int cc = c + kk * 256;
    orow[cc] = f2b(b2f(src[cc]) + pr[cc]);
  }
}

// t2s_full[bt*197 + j] = (j==0) ? sn[bt*197] : proj3[(b*196 + (j-1))*8 + t]
__global__ __launch_bounds__(256) void scatter_t2s_kernel(
    const u16* __restrict__ proj3, const u16* __restrict__ sn, u16* __restrict__ out)
{
  int r = blockIdx.x, c = threadIdx.x;
  int bt = r / 197, j = r - bt * 197;
  const u16* src;
  if (j == 0) {
    src = sn + (size_t)r * 768;
  } else {
    int b = bt >> 3, t = bt & 7, n = j - 1;
    src = proj3 + (size_t)((b * 196 + n) * 8 + t) * 768;
  }
  u16* orow = out + (size_t)r * 768;
#pragma unroll
  for (int kk = 0; kk < 3; ++kk) {
    int cc = c + kk * 256;
    orow[cc] = src[cc];
  }
}

__global__ __launch_bounds__(256) void build_bias_kernel(
    const float* __restrict__ qb, const float* __restrict__ vb, float* __restrict__ out)
{
  int i = blockIdx.x * 256 + threadIdx.x;
  if (i >= 2304) return;
  out[i] = (i < 768) ? qb[i] : ((i < 1536) ? 0.f : vb[i - 1536]);
}

// ---------------- launcher ----------------
extern "C" void kernel_launch(void* const* d_in, const int* in_sizes, int n_in,
                              void* d_out, int out_size, void* d_ws, size_t ws_size,
                              hipStream_t stream) {
  (void)in_sizes; (void)n_in; (void)out_size; (void)ws_size;
  const float* s_x        = (const float*)d_in[0];
  const float* t_x        = (const float*)d_in[1];
  const float* ln1_g      = (const float*)d_in[2];
  const float* ln1_b      = (const float*)d_in[3];
  const float* qkv_w      = (const float*)d_in[4];
  const float* q_bias     = (const float*)d_in[5];
  const float* v_bias     = (const float*)d_in[6];
  const float* attn_proj_w= (const float*)d_in[7];
  const float* attn_proj_b= (const float*)d_in[8];
  const float* lns_g      = (const float*)d_in[9];
  const float* lns_b      = (const float*)d_in[10];
  const float* lnt_g      = (const float*)d_in[11];
  const float* lnt_b      = (const float*)d_in[12];
  const float* csp        = (const float*)d_in[13];
  const float* vsp        = (const float*)d_in[14];
  const float* s2t_q_w    = (const float*)d_in[15];
  const float* s2t_q_b    = (const float*)d_in[16];
  const float* s2t_kv_w   = (const float*)d_in[17];
  const float* s2t_kv_b   = (const float*)d_in[18];
  const float* s2t_proj_w = (const float*)d_in[19];
  const float* s2t_proj_b = (const float*)d_in[20];
  const float* s2t_a1_w   = (const float*)d_in[21];
  const float* s2t_a1_b   = (const float*)d_in[22];
  const float* s2t_a2_w   = (const float*)d_in[23];
  const float* s2t_a2_b   = (const float*)d_in[24];
  const float* ctp        = (const float*)d_in[25];
  const float* vtp        = (const float*)d_in[26];
  const float* t2s_q_w    = (const float*)d_in[27];
  const float* t2s_q_b    = (const float*)d_in[28];
  const float* t2s_kv_w   = (const float*)d_in[29];
  const float* t2s_kv_b   = (const float*)d_in[30];
  const float* t2s_proj_w = (const float*)d_in[31];
  const float* t2s_proj_b = (const float*)d_in[32];
  const float* t2s_a1_w   = (const float*)d_in[33];
  const float* t2s_a1_b   = (const float*)d_in[34];
  const float* t2s_a2_w   = (const float*)d_in[35];
  const float* t2s_a2_b   = (const float*)d_in[36];
  const float* ln2_g      = (const float*)d_in[37];
  const float* ln2_b      = (const float*)d_in[38];
  const float* mlp1_w     = (const float*)d_in[39];
  const float* mlp1_b     = (const float*)d_in[40];
  const float* mlp2_w     = (const float*)d_in[41];
  const float* mlp2_b     = (const float*)d_in[42];
  const float* ln2s_g     = (const float*)d_in[43];
  const float* ln2s_b     = (const float*)d_in[44];
  const float* smlp1_w    = (const float*)d_in[45];
  const float* smlp1_b    = (const float*)d_in[46];
  const float* smlp2_w    = (const float*)d_in[47];
  const float* smlp2_b    = (const float*)d_in[48];

  u16* ws = (u16*)d_ws;
  const size_t SLOT = 4841472;  // 6304*768
  u16* wA = ws;
  u16* wB = ws + SLOT;
  u16* wC = ws + 2 * SLOT;
  u16* wD = ws + 3 * SLOT;
  u16* wE = ws + 4 * SLOT;
  u16* wF = ws + 5 * SLOT;
  u16* wQ = ws + 6 * SLOT;                 // 19365888 elems: qkv / kv / mlp-hidden (disjoint lifetimes)

  // bf16 weight copies (converted once per launch from fp32 inputs)
  size_t wo = 6 * SLOT + 19365888;
  u16* cQKV = ws + wo; wo += 1769472;
  u16* cAP  = ws + wo; wo += 589824;
  u16* cS2Q = ws + wo; wo += 589824;
  u16* cS2KV= ws + wo; wo += 1179648;
  u16* cS2P = ws + wo; wo += 589824;
  u16* cS2A1= ws + wo; wo += 147456;
  u16* cS2A2= ws + wo; wo += 147456;
  u16* cT2Q = ws + wo; wo += 589824;
  u16* cT2KV= ws + wo; wo += 1179648;
  u16* cT2P = ws + wo; wo += 589824;
  u16* cT2A1= ws + wo; wo += 147456;
  u16* cT2A2= ws + wo; wo += 147456;
  u16* cM1  = ws + wo; wo += 2359296;
  u16* cM2  = ws + wo; wo += 2359296;
  u16* cSM1 = ws + wo; wo += 2359296;
  u16* cSM2 = ws + wo; wo += 2359296;
  float* fBias = (float*)(ws + wo);        // 2304 floats

  float* outS = (float*)d_out;             // fp32 output (reference output dtype)
  float* outT = outS + 4841472;

  const int Mt = 6272, Ms = 6304;

  CvtArgs ca;
  const float* srcs[16] = {qkv_w, attn_proj_w, s2t_q_w, s2t_kv_w, s2t_proj_w, s2t_a1_w, s2t_a2_w,
                           t2s_q_w, t2s_kv_w, t2s_proj_w, t2s_a1_w, t2s_a2_w, mlp1_w, mlp2_w, smlp1_w, smlp2_w};
  u16* dsts[16] = {cQKV, cAP, cS2Q, cS2KV, cS2P, cS2A1, cS2A2,
                   cT2Q, cT2KV, cT2P, cT2A1, cT2A2, cM1, cM2, cSM1, cSM2};
  int ns[16] = {1769472, 589824, 589824, 1179648, 589824, 147456, 147456,
                589824, 1179648, 589824, 147456, 147456, 2359296, 2359296, 2359296, 2359296};
  for (int i = 0; i < 16; ++i) { ca.src[i] = srcs[i]; ca.dst[i] = dsts[i]; ca.n[i] = ns[i]; }
  cvt_kernel<<<dim3(1152, 16), 256, 0, stream>>>(ca);
  build_bias_kernel<<<9, 256, 0, stream>>>(q_bias, v_bias, fBias);

  // t self-attention branch
  ln_kernel<true><<<1568, 256, 0, stream>>>(t_x, ln1_g, ln1_b, wA, Mt);
  gemm_nt<0,false,false><<<dim3(18, 49), 256, 0, stream>>>(wA, cQKV, fBias, wQ, nullptr, nullptr, Mt, 2304, 768);
  attn_kernel<<<dim3(49, 12, 4), 64, 0, stream>>>(wQ, 2304, wQ + 768, wQ + 1536, 2304, wB, 1568, 1568);
  gemm_nt<2,true,false><<<dim3(6, 49), 256, 0, stream>>>(wB, cAP, attn_proj_b, wC, t_x, nullptr, Mt, 768, 768); // t1 -> wC
  // norms
  ln_kernel<true><<<1576, 256, 0, stream>>>(s_x, lns_g, lns_b, wD, Ms);   // sn -> wD (long-lived)
  ln_kernel<false><<<1568, 256, 0, stream>>>(wC, lnt_g, lnt_b, wA, Mt);   // tn -> wA
  // s2t cross
  add_pos_mod_kernel<<<Mt, 256, 0, stream>>>(wA, vsp, wB, 196);    // tq -> wB
  gather_spat_kernel<<<Mt, 256, 0, stream>>>(wD, csp, wE);         // s_pat -> wE
  gemm_nt<0,false,false><<<dim3(6, 49), 256, 0, stream>>>(wB, cS2Q, s2t_q_b, wA, nullptr, nullptr, Mt, 768, 768);   // q2 -> wA
  gemm_nt<0,false,false><<<dim3(12, 49), 256, 0, stream>>>(wE, cS2KV, s2t_kv_b, wQ, nullptr, nullptr, Mt, 1536, 768); // kv2 -> wQ
  attn_kernel<<<dim3(7, 12, 32), 64, 0, stream>>>(wA, 768, wQ, wQ + 768, 1536, wB, 196, 196);              // attn2 -> wB
  gemm_nt<0,false,false><<<dim3(6, 49), 256, 0, stream>>>(wB, cS2P, s2t_proj_b, wE, nullptr, nullptr, Mt, 768, 768); // s2t -> wE
  gemm_nt<1,false,false><<<dim3(2, 49), 256, 0, stream>>>(wE, cS2A1, s2t_a1_b, wF, nullptr, nullptr, Mt, 192, 768);  // h -> wF
  gemm_nt<3,false,false><<<dim3(6, 49), 256, 0, stream>>>(wF, cS2A2, s2t_a2_b, wB, wC, wE, Mt, 768, 192);            // t2 -> wB
  // t2s cross
  ln_kernel<false><<<1568, 256, 0, stream>>>(wB, lnt_g, lnt_b, wA, Mt);   // tn2 -> wA
  gather_spt2_kernel<<<Mt, 256, 0, stream>>>(wD, ctp, wC);         // spt2 -> wC
  gather_tt2_kernel<<<Mt, 256, 0, stream>>>(wA, vtp, wE);          // tt2 -> wE
  gemm_nt<0,false,false><<<dim3(6, 49), 256, 0, stream>>>(wC, cT2Q, t2s_q_b, wA, nullptr, nullptr, Mt, 768, 768);     // q3 -> wA
  gemm_nt<0,false,false><<<dim3(12, 49), 256, 0, stream>>>(wE, cT2KV, t2s_kv_b, wQ, nullptr, nullptr, Mt, 1536, 768); // kv3 -> wQ
  attn_small_kernel<<<2352, 256, 0, stream>>>(wA, wQ, wC);         // attn3 -> wC
  gemm_nt<0,false,false><<<dim3(6, 49), 256, 0, stream>>>(wC, cT2P, t2s_proj_b, wE, nullptr, nullptr, Mt, 768, 768);  // proj3 -> wE
  scatter_t2s_kernel<<<Ms, 256, 0, stream>>>(wE, wD, wF);          // t2s_full -> wF
  gemm_nt<1,false,false><<<dim3(2, 50), 256, 0, stream>>>(wF, cT2A1, t2s_a1_b, wA, nullptr, nullptr, Ms, 192, 768);   // h2 -> wA
  gemm_nt<3,true,false><<<dim3(6, 50), 256, 0, stream>>>(wA, cT2A2, t2s_a2_b, wC, s_x, wF, Ms, 768, 192);             // s2 -> wC
  // t MLP
  ln_kernel<false><<<1568, 256, 0, stream>>>(wB, ln2_g, ln2_b, wD, Mt);
  gemm_nt<1,false,false><<<dim3(24, 49), 256, 0, stream>>>(wD, cM1, mlp1_b, wQ, nullptr, nullptr, Mt, 3072, 768);
  gemm_nt<2,false,true><<<dim3(6, 49), 256, 0, stream>>>(wQ, cM2, mlp2_b, outT, wB, nullptr, Mt, 768, 3072);
  // s MLP
  ln_kernel<false><<<1576, 256, 0, stream>>>(wC, ln2s_g, ln2s_b, wD, Ms);
  gemm_nt<1,false,false><<<dim3(24, 50), 256, 0, stream>>>(wD, cSM1, smlp1_b, wQ, nullptr, nullptr, Ms, 3072, 768);
  gemm_nt<2,false,true><<<dim3(6, 50), 256, 0, stream>>>(wQ, cSM2, smlp2_b, outS, wC, nullptr, Ms, 768, 3072);
}